// Round 3
// baseline (205.261 us; speedup 1.0000x reference)
//
#include <hip/hip_runtime.h>
#include <cstdint>
#include <cstddef>

#define B_ 256
#define N_ 512
#define H_ 30
#define CAP 96
#define STR 33

typedef unsigned short u16;

// ---------------- workspace layout (bytes), ~27 MB ----------------
constexpr size_t O_COLIDX = 0;          // u16 [131072*96]
constexpr size_t O_ROWCNT = 25165824;   // int [131072]
constexpr size_t O_DIS    = 25690112;   // f32 [131072]
constexpr size_t O_DIAG   = 26214400;   // f32 [131072]
constexpr size_t O_XP     = 26738688;   // f32 [256*240]
constexpr size_t O_AP     = 26984448;   // f32 [256*64]

// ---------------- pass 1: read adj ONCE, build sparse structure ----------------
__global__ __launch_bounds__(256) void build_sparse(
    const float* __restrict__ adj, u16* __restrict__ colidx,
    int* __restrict__ rowcnt, float* __restrict__ dis, float* __restrict__ diagv)
{
    int row  = blockIdx.x * 4 + (threadIdx.x >> 6);
    int lane = threadIdx.x & 63;
    int i    = row & (N_ - 1);
    const float4* arow = (const float4*)(adj + (size_t)row * N_);
    float4 v0 = arow[lane];
    float4 v1 = arow[lane + 64];
    float vals[8] = {v0.x, v0.y, v0.z, v0.w, v1.x, v1.y, v1.z, v1.w};

    float sum = 0.f, dloc = 0.f;
    int cnt = 0;
    #pragma unroll
    for (int k = 0; k < 8; ++k) {
        int jc = (k < 4) ? (lane * 4 + k) : (256 + lane * 4 + (k - 4));
        float v = vals[k];
        if (jc == i) dloc = v;
        else { sum += v; if (v != 0.f) ++cnt; }
    }
    int pre = cnt;
    #pragma unroll
    for (int d = 1; d < 64; d <<= 1) { int y = __shfl_up(pre, d, 64); if (lane >= d) pre += y; }
    int excl  = pre - cnt;
    int total = __shfl(pre, 63, 64);
    #pragma unroll
    for (int d = 32; d > 0; d >>= 1) { sum += __shfl_xor(sum, d, 64); dloc += __shfl_xor(dloc, d, 64); }

    u16* cb = colidx + (size_t)row * CAP;
    int c2 = 0;
    #pragma unroll
    for (int k = 0; k < 8; ++k) {
        int jc = (k < 4) ? (lane * 4 + k) : (256 + lane * 4 + (k - 4));
        float v = vals[k];
        if (jc != i && v != 0.f) { int p = excl + c2; if (p < CAP) cb[p] = (u16)jc; ++c2; }
    }
    if (lane == 0) {
        rowcnt[row] = total > CAP ? CAP : total;
        dis[row]    = rsqrtf(fmaxf(1.f, sum + 1.f));
        diagv[row]  = dloc;
    }
}

// one GCN layer at n=512: xr (registers, FIN wide) -> xr (30 wide).
// XB layout [512][STR=33]: odd stride => bank = (j2 + h) & 31, random j2 across
// lanes -> ~2 lanes/bank (free per m136). Scalar b32 reads/writes only.
template <int FIN, bool RELU>
__device__ __forceinline__ void gcn_layer(
    int j, float di, int cnt, const uint4* cp, float* __restrict__ XB,
    const float* __restrict__ Wg, const float* __restrict__ bg, float* xr)
{
    float acc[30];
    #pragma unroll
    for (int h = 0; h < 30; ++h) acc[h] = 0.f;
    #pragma unroll
    for (int f = 0; f < FIN; ++f) {
        float xv = xr[f];
        #pragma unroll
        for (int h = 0; h < 30; ++h) acc[h] = fmaf(xv, Wg[f * 30 + h], acc[h]);
    }
    #pragma unroll
    for (int h = 0; h < 30; ++h) { acc[h] *= di; XB[j * STR + h] = acc[h]; }
    __syncthreads();

    // gather: acc already holds the self-loop term (a_ii = 1)
    int nch = (cnt + 7) >> 3;
    uint4 cc = cp[0];
    for (int ch = 0; ch < nch; ++ch) {
        uint4 cn = cp[(ch + 1 < 12) ? (ch + 1) : 11];   // prefetch next chunk
        int kb = ch * 8;
        #define NBR(W, S, O) \
            if (kb + O < cnt) { int j2 = (int)(((W) >> (S)) & 0xffffu); int base = j2 * STR; \
                _Pragma("unroll") for (int h = 0; h < 30; ++h) acc[h] += XB[base + h]; }
        NBR(cc.x, 0, 0) NBR(cc.x, 16, 1)
        NBR(cc.y, 0, 2) NBR(cc.y, 16, 3)
        NBR(cc.z, 0, 4) NBR(cc.z, 16, 5)
        NBR(cc.w, 0, 6) NBR(cc.w, 16, 7)
        #undef NBR
        cc = cn;
    }
    #pragma unroll
    for (int h = 0; h < 30; ++h) {
        float r = fmaf(di, acc[h], bg[h]);
        if (RELU) r = fmaxf(r, 0.f);
        xr[h] = r;
    }
    __syncthreads();   // all XB reads done before next layer overwrites
}

// ---------------- mega: 4 GCN layers + DiffPool0, one block per batch ----------------
__global__ __launch_bounds__(512) void mega_kernel(
    const float* __restrict__ x0,
    const float* __restrict__ W0, const float* __restrict__ Bs0,
    const float* __restrict__ W1, const float* __restrict__ Bs1,
    const float* __restrict__ W2, const float* __restrict__ Bs2,
    const float* __restrict__ W3, const float* __restrict__ Bs3,
    const float* __restrict__ pw, const float* __restrict__ pb,
    const u16* __restrict__ colidx, const int* __restrict__ rowcnt,
    const float* __restrict__ dis, const float* __restrict__ diagv,
    float* __restrict__ xp, float* __restrict__ ap)
{
    __shared__ __align__(16) float XB[N_ * STR];   // propagation buffer / pool scratch
    __shared__ __align__(16) float X3[N_ * STR];   // final x3 for pooling
    int b = blockIdx.x, t = threadIdx.x, j = t;

    // stage own x0 row into registers (7 x float2)
    float xr[30];
    {
        const float2* xrow = (const float2*)(x0 + ((size_t)b * N_ + j) * 14);
        #pragma unroll
        for (int k = 0; k < 7; ++k) {
            float2 v = xrow[k];
            xr[2 * k] = v.x; xr[2 * k + 1] = v.y;
        }
    }
    float di = dis[(size_t)b * N_ + j];
    int cnt  = rowcnt[(size_t)b * N_ + j];
    const uint4* cp = (const uint4*)(colidx + ((size_t)b * N_ + j) * CAP);

    gcn_layer<14, true >(j, di, cnt, cp, XB, W0, Bs0, xr);
    gcn_layer<30, true >(j, di, cnt, cp, XB, W1, Bs1, xr);
    gcn_layer<30, true >(j, di, cnt, cp, XB, W2, Bs2, xr);
    gcn_layer<30, false>(j, di, cnt, cp, XB, W3, Bs3, xr);

    // write x3 row for pooling (pad cols 30..32 to keep later reads clean)
    #pragma unroll
    for (int h = 0; h < 30; ++h) X3[j * STR + h] = xr[h];
    X3[j * STR + 30] = 0.f; X3[j * STR + 31] = 0.f; X3[j * STR + 32] = 0.f;

    // pool scratch aliases XB (dead after last gather barrier)
    float* ls  = XB;                    // [512*9] logits / s
    float* ltp = XB + N_ * 9;           // [512*9] A_raw · s   (stride 9!)
    float* red = XB + N_ * 18;          // [2048] partials, 16B aligned

    // logits from register row
    {
        float lg[8];
        #pragma unroll
        for (int c = 0; c < 8; ++c) lg[c] = pb[c];
        #pragma unroll
        for (int h = 0; h < 30; ++h) {
            float xv = xr[h];
            #pragma unroll
            for (int c = 0; c < 8; ++c) lg[c] = fmaf(xv, pw[h * 8 + c], lg[c]);
        }
        #pragma unroll
        for (int c = 0; c < 8; ++c) ls[j * 9 + c] = lg[c];
    }
    __syncthreads();
    // softmax over nodes (axis=1): wave w handles c=w
    {
        int c = t >> 6, lane = t & 63;
        float v[8]; float mx = -1e30f;
        #pragma unroll
        for (int k = 0; k < 8; ++k) { v[k] = ls[(k * 64 + lane) * 9 + c]; mx = fmaxf(mx, v[k]); }
        #pragma unroll
        for (int d = 32; d > 0; d >>= 1) mx = fmaxf(mx, __shfl_xor(mx, d, 64));
        float sm = 0.f;
        #pragma unroll
        for (int k = 0; k < 8; ++k) { v[k] = __expf(v[k] - mx); sm += v[k]; }
        #pragma unroll
        for (int d = 32; d > 0; d >>= 1) sm += __shfl_xor(sm, d, 64);
        float inv = 1.f / sm;
        #pragma unroll
        for (int k = 0; k < 8; ++k) ls[(k * 64 + lane) * 9 + c] = v[k] * inv;
    }
    __syncthreads();
    // softmax over clusters (axis=-1): thread per node
    {
        float v[8]; float mx = -1e30f;
        #pragma unroll
        for (int c = 0; c < 8; ++c) { v[c] = ls[j * 9 + c]; mx = fmaxf(mx, v[c]); }
        float sm = 0.f;
        #pragma unroll
        for (int c = 0; c < 8; ++c) { v[c] = __expf(v[c] - mx); sm += v[c]; }
        float inv = 1.f / sm;
        #pragma unroll
        for (int c = 0; c < 8; ++c) ls[j * 9 + c] = v[c] * inv;
    }
    __syncthreads();
    // ltp[n][d] = (A_raw · s)[n][d] via sparse + stored diagonal
    {
        float a8[8];
        float dg = diagv[(size_t)b * N_ + j];
        #pragma unroll
        for (int d = 0; d < 8; ++d) a8[d] = dg * ls[j * 9 + d];
        int nch = (cnt + 7) >> 3;
        uint4 cc = cp[0];
        for (int ch = 0; ch < nch; ++ch) {
            uint4 cn = cp[(ch + 1 < 12) ? (ch + 1) : 11];
            int kb = ch * 8;
            #define LTNBR(W, S, O) \
                if (kb + O < cnt) { int j2 = (int)(((W) >> (S)) & 0xffffu); \
                    _Pragma("unroll") for (int d = 0; d < 8; ++d) a8[d] += ls[j2 * 9 + d]; }
            LTNBR(cc.x, 0, 0) LTNBR(cc.x, 16, 1)
            LTNBR(cc.y, 0, 2) LTNBR(cc.y, 16, 3)
            LTNBR(cc.z, 0, 4) LTNBR(cc.z, 16, 5)
            LTNBR(cc.w, 0, 6) LTNBR(cc.w, 16, 7)
            #undef LTNBR
            cc = cn;
        }
        #pragma unroll
        for (int d = 0; d < 8; ++d) ltp[j * 9 + d] = a8[d];
    }
    __syncthreads();
    // xp partials: xp[c][f] = sum_n s[n][c] x3[n][f]; seg = 64-node range
    {
        int seg = t >> 6, cd = t & 63, c = cd >> 3, dd = cd & 7;
        float a0 = 0.f, a1 = 0.f, a2 = 0.f, a3 = 0.f;
        for (int n = seg * 64; n < seg * 64 + 64; ++n) {
            float sv = ls[n * 9 + c];
            int base = n * STR + dd * 4;
            a0 = fmaf(sv, X3[base + 0], a0);
            a1 = fmaf(sv, X3[base + 1], a1);
            a2 = fmaf(sv, X3[base + 2], a2);
            a3 = fmaf(sv, X3[base + 3], a3);
        }
        *(float4*)&red[t * 4] = make_float4(a0, a1, a2, a3);
    }
    __syncthreads();
    if (t < 240) {
        int c = t / 30, f = t - c * 30, dd = f >> 2, m = f & 3;
        float s1 = 0.f;
        #pragma unroll
        for (int seg = 0; seg < 8; ++seg) s1 += red[(seg * 64 + c * 8 + dd) * 4 + m];
        xp[(size_t)b * 240 + t] = s1;
    }
    __syncthreads();
    // ap partials: ap[c][d] = sum_n s[n][c] ltp[n][d]
    {
        int seg = t >> 6, cd = t & 63, c = cd >> 3, d = cd & 7;
        float s1 = 0.f;
        for (int n = seg * 64; n < seg * 64 + 64; ++n)
            s1 = fmaf(ls[n * 9 + c], ltp[n * 9 + d], s1);
        red[t] = s1;
    }
    __syncthreads();
    if (t < 64) {
        float s1 = 0.f;
        #pragma unroll
        for (int k = 0; k < 8; ++k) s1 += red[k * 64 + t];
        ap[(size_t)b * 64 + t] = s1;
    }
}

// ---------------- tail: levels n=8,4,2,1 entirely in LDS, one block per batch ----------------
__device__ void gcn_small(int n, int t, const float* X, float* XN, float* XW, float* DIS,
                          const float* A, const float* W, const float* Bias, bool relu)
{
    if (t < n) {
        float s = 1.f;
        for (int jj = 0; jj < n; ++jj) if (jj != t) s += A[t * 8 + jj];
        DIS[t] = rsqrtf(fmaxf(1.f, s));
    }
    __syncthreads();
    if (t < n * 30) {
        int i = t / 30, h = t - i * 30;
        float acc = 0.f;
        #pragma unroll
        for (int f = 0; f < 30; ++f) acc += X[i * 30 + f] * W[f * 30 + h];
        XW[t] = acc * DIS[i];
    }
    __syncthreads();
    if (t < n * 30) {
        int i = t / 30, h = t - i * 30;
        float acc = XW[i * 30 + h];
        for (int jj = 0; jj < n; ++jj) if (jj != i) acc += A[i * 8 + jj] * XW[jj * 30 + h];
        float r = DIS[i] * acc + Bias[h];
        if (relu) r = fmaxf(r, 0.f);
        XN[t] = r;
    }
    __syncthreads();
}

__device__ void pool_small(int n, int c, int t, const float* X, const float* A,
                           const float* PW, const float* PB,
                           float* S, float* T, float* LG, float* XN, float* AN)
{
    if (t < n * c) {
        int i = t / c, k = t - i * c;
        float acc = PB[k];
        #pragma unroll
        for (int h = 0; h < 30; ++h) acc += X[i * 30 + h] * PW[h * c + k];
        LG[i * 8 + k] = acc;
    }
    __syncthreads();
    if (t < c) {
        float mx = -1e30f;
        for (int i = 0; i < n; ++i) mx = fmaxf(mx, LG[i * 8 + t]);
        float sm = 0.f;
        for (int i = 0; i < n; ++i) { float e = __expf(LG[i * 8 + t] - mx); LG[i * 8 + t] = e; sm += e; }
        float inv = 1.f / sm;
        for (int i = 0; i < n; ++i) LG[i * 8 + t] *= inv;
    }
    __syncthreads();
    if (t < n) {
        float mx = -1e30f;
        for (int k = 0; k < c; ++k) mx = fmaxf(mx, LG[t * 8 + k]);
        float sm = 0.f;
        for (int k = 0; k < c; ++k) { float e = __expf(LG[t * 8 + k] - mx); S[t * 8 + k] = e; sm += e; }
        float inv = 1.f / sm;
        for (int k = 0; k < c; ++k) S[t * 8 + k] *= inv;
    }
    __syncthreads();
    if (t < c * 30) {
        int k = t / 30, f = t - k * 30;
        float acc = 0.f;
        for (int i = 0; i < n; ++i) acc += S[i * 8 + k] * X[i * 30 + f];
        XN[t] = acc;
    }
    if (t < n * c) {
        int i = t / c, d = t - i * c;
        float acc = 0.f;
        for (int m = 0; m < n; ++m) acc += A[i * 8 + m] * S[m * 8 + d];
        T[i * 8 + d] = acc;
    }
    __syncthreads();
    if (t < c * c) {
        int k = t / c, d = t - k * c;
        float acc = 0.f;
        for (int i = 0; i < n; ++i) acc += S[i * 8 + k] * T[i * 8 + d];
        AN[k * 8 + d] = acc;
    }
    __syncthreads();
}

__global__ __launch_bounds__(256) void tail_kernel(
    const float* __restrict__ xp0, const float* __restrict__ ap0,
    const float* cw4, const float* cb4, const float* cw5, const float* cb5,
    const float* cw6, const float* cb6, const float* cw7, const float* cb7,
    const float* pw1, const float* pb1, const float* pw2, const float* pb2,
    const float* pw3, const float* pb3, const float* lw, const float* lb,
    float* __restrict__ out)
{
    __shared__ float bufX[240], bufY[240], XW[240], DIS[8];
    __shared__ float bufA[64], bufB[64], S[64], T[64], LG[64];
    int b = blockIdx.x, t = threadIdx.x;
    if (t < 240) bufX[t] = xp0[(size_t)b * 240 + t];
    if (t < 64)  bufA[t] = ap0[(size_t)b * 64 + t];
    __syncthreads();
    float *X = bufX, *XN = bufY, *A = bufA, *AN = bufB;

    gcn_small(8, t, X, XN, XW, DIS, A, cw4, cb4, true);   { float* tmp = X; X = XN; XN = tmp; }
    pool_small(8, 4, t, X, A, pw1, pb1, S, T, LG, XN, AN); { float* tmp = X; X = XN; XN = tmp; tmp = A; A = AN; AN = tmp; }
    gcn_small(4, t, X, XN, XW, DIS, A, cw5, cb5, true);   { float* tmp = X; X = XN; XN = tmp; }
    pool_small(4, 2, t, X, A, pw2, pb2, S, T, LG, XN, AN); { float* tmp = X; X = XN; XN = tmp; tmp = A; A = AN; AN = tmp; }
    gcn_small(2, t, X, XN, XW, DIS, A, cw6, cb6, true);   { float* tmp = X; X = XN; XN = tmp; }
    pool_small(2, 1, t, X, A, pw3, pb3, S, T, LG, XN, AN); { float* tmp = X; X = XN; XN = tmp; tmp = A; A = AN; AN = tmp; }
    gcn_small(1, t, X, XN, XW, DIS, A, cw7, cb7, true);   { float* tmp = X; X = XN; XN = tmp; }

    if (t < 2) {
        float acc = lb[t];
        #pragma unroll
        for (int h = 0; h < 30; ++h) acc += X[h] * lw[h * 2 + t];
        out[(size_t)b * 2 + t] = acc;
    }
}

// ---------------- launch ----------------
extern "C" void kernel_launch(void* const* d_in, const int* in_sizes, int n_in,
                              void* d_out, int out_size, void* d_ws, size_t ws_size,
                              hipStream_t stream)
{
    const float* x   = (const float*)d_in[0];
    const float* adj = (const float*)d_in[1];
    const float *cw[8], *cb[8], *pw[4], *pb[4];
    for (int i = 0; i < 8; ++i) { cw[i] = (const float*)d_in[4 + 2 * i]; cb[i] = (const float*)d_in[5 + 2 * i]; }
    for (int i = 0; i < 4; ++i) { pw[i] = (const float*)d_in[20 + 2 * i]; pb[i] = (const float*)d_in[21 + 2 * i]; }
    const float* lw = (const float*)d_in[28];
    const float* lb = (const float*)d_in[29];

    char* ws = (char*)d_ws;
    u16*   colidx = (u16*)(ws + O_COLIDX);
    int*   rowcnt = (int*)(ws + O_ROWCNT);
    float* dis0   = (float*)(ws + O_DIS);
    float* diag0  = (float*)(ws + O_DIAG);
    float* xp0    = (float*)(ws + O_XP);
    float* ap0    = (float*)(ws + O_AP);

    build_sparse<<<(B_ * N_) / 4, 256, 0, stream>>>(adj, colidx, rowcnt, dis0, diag0);
    mega_kernel <<<B_, 512, 0, stream>>>(x,
        cw[0], cb[0], cw[1], cb[1], cw[2], cb[2], cw[3], cb[3],
        pw[0], pb[0], colidx, rowcnt, dis0, diag0, xp0, ap0);
    tail_kernel <<<B_, 256, 0, stream>>>(xp0, ap0,
        cw[4], cb[4], cw[5], cb[5], cw[6], cb[6], cw[7], cb[7],
        pw[1], pb[1], pw[2], pb[2], pw[3], pb[3], lw, lb, (float*)d_out);
}